// Round 3
// baseline (49.723 us; speedup 1.0000x reference)
//
#include <hip/hip_runtime.h>

// Output = encode_output.sum(axis=1): [B, S, EOUT] -> [B, 1, EOUT]
// (softmax over a size-1 axis == 1.0, so the MLP branch is dead code)
//
// Single kernel, max-occupancy variant:
//   1024 blocks (4/CU) x 512 threads (8 waves) = 32 waves/CU (device max).
//   Block (b, ec) owns a 32-float output chunk; 64-way s-split per block;
//   each thread: 32 nontemporal float4 loads into 4 accumulators.
//   LDS tree reduce (float4, conflict-free) -> one float4 store per lane<8.

constexpr int B_   = 32;
constexpr int S_   = 2048;
constexpr int EOUT = 1024;        // 2 * ENC_H
constexpr int RS   = EOUT / 4;    // row stride in float4 = 256
constexpr int ECH  = 32;          // e-chunks per batch (32 floats each)
constexpr int TPB  = 512;
constexpr int SSPL = TPB / 8;     // 64-way s-split

typedef float f4v __attribute__((ext_vector_type(4)));

__global__ __launch_bounds__(TPB) void rowsum_kernel(const float* __restrict__ enc,
                                                     float* __restrict__ out) {
    const int bx  = blockIdx.x;
    const int b   = bx >> 5;          // / ECH
    const int ec  = bx & (ECH - 1);
    const int tid = threadIdx.x;
    const int e4  = tid & 7;          // float4 within the 32-float chunk
    const int ss  = tid >> 3;         // 0..63 s-split lane

    const f4v* base = reinterpret_cast<const f4v*>(enc + (size_t)b * S_ * EOUT + ec * 32) + e4;

    f4v a0 = {0.f,0.f,0.f,0.f};
    f4v a1 = {0.f,0.f,0.f,0.f};
    f4v a2 = {0.f,0.f,0.f,0.f};
    f4v a3 = {0.f,0.f,0.f,0.f};

    // rows s = ss + k*64; 32 loads/thread, 4 independent chains
    #pragma unroll
    for (int s = 0; s < S_; s += 4 * SSPL) {
        a0 += __builtin_nontemporal_load(base + (size_t)(s + ss) * RS);
        a1 += __builtin_nontemporal_load(base + (size_t)(s + ss + SSPL) * RS);
        a2 += __builtin_nontemporal_load(base + (size_t)(s + ss + 2 * SSPL) * RS);
        a3 += __builtin_nontemporal_load(base + (size_t)(s + ss + 3 * SSPL) * RS);
    }
    f4v acc = (a0 + a1) + (a2 + a3);

    __shared__ f4v lds[TPB];
    lds[tid] = acc;
    __syncthreads();

    #pragma unroll
    for (int off = TPB / 2; off >= 8; off >>= 1) {
        if (tid < off) {
            f4v t = lds[tid + off];
            lds[tid] += t;
        }
        __syncthreads();
    }

    if (tid < 8) {
        f4v r = lds[tid];
        reinterpret_cast<f4v*>(out + (size_t)b * EOUT + ec * 32)[tid] = r;
    }
}

extern "C" void kernel_launch(void* const* d_in, const int* in_sizes, int n_in,
                              void* d_out, int out_size, void* d_ws, size_t ws_size,
                              hipStream_t stream) {
    const float* enc = (const float*)d_in[0];
    float* out = (float*)d_out;
    rowsum_kernel<<<dim3(B_ * ECH), dim3(TPB), 0, stream>>>(enc, out);
}